// Round 14
// baseline (218.871 us; speedup 1.0000x reference)
//
#include <hip/hip_runtime.h>
#include <hip/hip_bf16.h>
#include <hip/hip_fp16.h>
#include <math.h>

// N=20000, E=320000, layers: [N,256]@[256,256] GEMMs, HEADS=2, HID=128.
#define NCH 256
#define LEAKY 0.2f

typedef __attribute__((ext_vector_type(8))) _Float16 half8_t;  // 4 VGPRs
typedef __attribute__((ext_vector_type(2))) _Float16 half2_t;
typedef __attribute__((ext_vector_type(4))) float f32x4;       // MFMA C/D

static __device__ __forceinline__ half2_t u2h2(unsigned u) {
    return __builtin_bit_cast(half2_t, u);
}

// pack 8 fp32 -> fp16 hi + fp16 lo (hi+lo covers 22 mantissa bits)
static __device__ __forceinline__ void f32_to_hl8(const float4 a, const float4 b,
                                                  uint4& h, uint4& l) {
    float f[8] = {a.x, a.y, a.z, a.w, b.x, b.y, b.z, b.w};
    unsigned hs[8], ls[8];
    #pragma unroll
    for (int c = 0; c < 8; ++c) {
        __half hh = __float2half_rn(f[c]);
        hs[c] = __half_as_ushort(hh);
        ls[c] = __half_as_ushort(__float2half_rn(f[c] - __half2float(hh)));
    }
    h = make_uint4(hs[0] | (hs[1] << 16), hs[2] | (hs[3] << 16),
                   hs[4] | (hs[5] << 16), hs[6] | (hs[7] << 16));
    l = make_uint4(ls[0] | (ls[1] << 16), ls[2] | (ls[3] << 16),
                   ls[4] | (ls[5] << 16), ls[6] | (ls[7] << 16));
}

// ---------------------------------------------------------------------------
// CSR build: counts (int4-vectorized; counts zeroed by wsplit_kernel which
// runs first on the serial stream) -> scan (4 elem/thread) -> scatter.
// ---------------------------------------------------------------------------
__global__ void count_kernel(const int* __restrict__ ei, int E, int n,
                             int* __restrict__ counts) {
    int tid = blockIdx.x * 256 + threadIdx.x;
    int E4 = E >> 2;                    // E divisible by 4 here (320000)
    if (tid < E4) {
        int4 d = ((const int4*)(ei + E))[tid];
        atomicAdd(&counts[d.x], 1);
        atomicAdd(&counts[d.y], 1);
        atomicAdd(&counts[d.z], 1);
        atomicAdd(&counts[d.w], 1);
    } else {
        int s = tid - E4;               // self loops
        if (s < n) atomicAdd(&counts[s], 1);
    }
}

__global__ void scan_kernel(const int* __restrict__ counts,
                            int* __restrict__ offsets,
                            int* __restrict__ cursor, int n) {
    __shared__ int wsum[16];
    int tid  = threadIdx.x;          // 1024 threads = 16 waves, 4 elem/thread
    int lane = tid & 63, w = tid >> 6;
    int carry = 0;
    for (int base = 0; base < n; base += 4096) {
        int i0 = base + tid * 4;
        int v0 = 0, v1 = 0, v2 = 0, v3 = 0;
        if (i0 + 3 < n) {
            int4 v = *(const int4*)&counts[i0];
            v0 = v.x; v1 = v.y; v2 = v.z; v3 = v.w;
        } else if (i0 < n) {
            v0 = counts[i0];
            if (i0 + 1 < n) v1 = counts[i0 + 1];
            if (i0 + 2 < n) v2 = counts[i0 + 2];
        }
        int c1 = v0 + v1, c2 = c1 + v2, c3 = c2 + v3;
        int tsum = c3;
        int incl = tsum;
        #pragma unroll
        for (int off = 1; off < 64; off <<= 1) {
            int t2 = __shfl_up(incl, off, 64);
            if (lane >= off) incl += t2;
        }
        if (lane == 63) wsum[w] = incl;
        __syncthreads();
        if (w == 0 && lane < 16) {
            int s = wsum[lane];
            #pragma unroll
            for (int off = 1; off < 16; off <<= 1) {
                int t2 = __shfl_up(s, off, 64);
                if (lane >= off) s += t2;
            }
            wsum[lane] = s;
        }
        __syncthreads();
        int wpre = (w == 0) ? 0 : wsum[w - 1];
        int excl = carry + wpre + incl - tsum;
        if (i0 + 3 < n) {
            int4 o = make_int4(excl, excl + v0, excl + c1, excl + c2);
            *(int4*)&offsets[i0] = o;
            *(int4*)&cursor[i0]  = o;
        } else if (i0 < n) {
            offsets[i0] = excl;           cursor[i0] = excl;
            if (i0 + 1 < n) { offsets[i0 + 1] = excl + v0; cursor[i0 + 1] = excl + v0; }
            if (i0 + 2 < n) { offsets[i0 + 2] = excl + c1; cursor[i0 + 2] = excl + c1; }
        }
        carry += wsum[15];
        __syncthreads();
    }
    if (tid == 0) offsets[n] = carry;
}

__global__ void scatter_kernel(const int* __restrict__ ei, int E, int n,
                               int* __restrict__ cursor,
                               int* __restrict__ csr_src) {
    int tid = blockIdx.x * 256 + threadIdx.x;
    int E4 = E >> 2;
    if (tid < E4) {
        int4 s = ((const int4*)ei)[tid];
        int4 d = ((const int4*)(ei + E))[tid];
        csr_src[atomicAdd(&cursor[d.x], 1)] = s.x;
        csr_src[atomicAdd(&cursor[d.y], 1)] = s.y;
        csr_src[atomicAdd(&cursor[d.z], 1)] = s.z;
        csr_src[atomicAdd(&cursor[d.w], 1)] = s.w;
    } else {
        int i = tid - E4;               // self loops
        if (i < n) csr_src[atomicAdd(&cursor[i], 1)] = i;
    }
}

// ---------------------------------------------------------------------------
// Weight transpose: W[256,256] (k-major) -> Wt[256,256] (n-major) fp16.
// Also zeroes counts[] (runs FIRST; stream order makes this safe and saves
// a dedicated zero dispatch).
// ---------------------------------------------------------------------------
struct WPtrs { const float* w[6]; };
__global__ __launch_bounds__(1024) void wsplit_kernel(WPtrs p,
        __half* __restrict__ wt, int* __restrict__ counts, int n) {
    int gid = ((blockIdx.z * gridDim.y + blockIdx.y) * gridDim.x + blockIdx.x) * 1024
              + threadIdx.y * 32 + threadIdx.x;
    if (gid < n) counts[gid] = 0;

    __shared__ float tile[32][33];
    int m = blockIdx.z;
    const float* W = p.w[m];
    size_t base = (size_t)m * 65536;
    int k = blockIdx.y * 32 + threadIdx.y;
    int nn = blockIdx.x * 32 + threadIdx.x;
    tile[threadIdx.y][threadIdx.x] = W[k * NCH + nn];
    __syncthreads();
    int on = blockIdx.x * 32 + threadIdx.y;
    int ok = blockIdx.y * 32 + threadIdx.x;
    wt[base + (size_t)on * NCH + ok] = __float2half_rn(tile[threadIdx.x][threadIdx.y]);
}

// ---------------------------------------------------------------------------
// MFMA dual GEMM, fp16 2-product split: C = Ahi*B + Alo*B (B single fp16).
// AF32: A is fp32 (layer 1), hi/lo split in-register during staging.
// Flat grid with L2-reuse swizzle (stripes of 32 = 8 row-tiles x 4 cbs).
// xl written fp16 (gather side), xr fp32.  (R11/R13-proven version.)
// ---------------------------------------------------------------------------
#define LDK 40
template <int AF32>
__global__ __launch_bounds__(256) void dual_gemm_mfma(
        const float* __restrict__ Af,
        const __half* __restrict__ Ahi, const __half* __restrict__ Alo,
        const __half* __restrict__ Bt,
        __half* __restrict__ xlh, float* __restrict__ xr, int M) {
    __shared__ ushort As[2][128 * LDK];
    __shared__ ushort Bs[128 * LDK];
    int b = blockIdx.x;
    int stripe = b >> 5;
    int wslot  = b & 31;
    int rt = (stripe << 3) + (wslot & 7);
    int cb = wslot >> 3;
    int row0 = rt * 128;
    if (row0 >= M) return;
    const __half* Bm = Bt + (size_t)(cb >> 1) * 65536;
    int col0 = (cb & 1) * 128;
    int t = threadIdx.x;
    int lane = t & 63, w = t >> 6;
    int wr = w >> 1, wc = w & 1;
    int l15 = lane & 15, l4 = lane >> 4;

    f32x4 acc[4][4];
    #pragma unroll
    for (int i = 0; i < 4; ++i)
        #pragma unroll
        for (int j = 0; j < 4; ++j) acc[i][j] = (f32x4){0.f, 0.f, 0.f, 0.f};

    int r0 = t >> 2,          q0 = (t & 3) * 8;
    int r1 = (t + 256) >> 2,  q1 = ((t + 256) & 3) * 8;

    for (int k0 = 0; k0 < 256; k0 += 32) {
        uint4 z = make_uint4(0, 0, 0, 0);
        uint4 a0h = z, a0l = z, a1h = z, a1l = z;
        if (row0 + r0 < M) {
            if (AF32) {
                float4 fa = *(const float4*)&Af[(size_t)(row0 + r0) * NCH + k0 + q0];
                float4 fb = *(const float4*)&Af[(size_t)(row0 + r0) * NCH + k0 + q0 + 4];
                f32_to_hl8(fa, fb, a0h, a0l);
            } else {
                a0h = *(const uint4*)&Ahi[(size_t)(row0 + r0) * NCH + k0 + q0];
                a0l = *(const uint4*)&Alo[(size_t)(row0 + r0) * NCH + k0 + q0];
            }
        }
        if (row0 + r1 < M) {
            if (AF32) {
                float4 fa = *(const float4*)&Af[(size_t)(row0 + r1) * NCH + k0 + q1];
                float4 fb = *(const float4*)&Af[(size_t)(row0 + r1) * NCH + k0 + q1 + 4];
                f32_to_hl8(fa, fb, a1h, a1l);
            } else {
                a1h = *(const uint4*)&Ahi[(size_t)(row0 + r1) * NCH + k0 + q1];
                a1l = *(const uint4*)&Alo[(size_t)(row0 + r1) * NCH + k0 + q1];
            }
        }
        uint4 b0 = *(const uint4*)&Bm[(size_t)(col0 + r0) * NCH + k0 + q0];
        uint4 b1 = *(const uint4*)&Bm[(size_t)(col0 + r1) * NCH + k0 + q1];
        __syncthreads();
        *(uint4*)&As[0][r0 * LDK + q0] = a0h;
        *(uint4*)&As[1][r0 * LDK + q0] = a0l;
        *(uint4*)&As[0][r1 * LDK + q1] = a1h;
        *(uint4*)&As[1][r1 * LDK + q1] = a1l;
        *(uint4*)&Bs[r0 * LDK + q0] = b0;
        *(uint4*)&Bs[r1 * LDK + q1] = b1;
        __syncthreads();

        half8_t af[4][2], bq[4];
        #pragma unroll
        for (int fm = 0; fm < 4; ++fm) {
            int addr = (wr * 64 + fm * 16 + l15) * LDK + l4 * 8;
            af[fm][0] = *(const half8_t*)&As[0][addr];
            af[fm][1] = *(const half8_t*)&As[1][addr];
        }
        #pragma unroll
        for (int fn = 0; fn < 4; ++fn) {
            int addr = (wc * 64 + fn * 16 + l15) * LDK + l4 * 8;
            bq[fn] = *(const half8_t*)&Bs[addr];
        }
        #pragma unroll
        for (int fm = 0; fm < 4; ++fm)
            #pragma unroll
            for (int fn = 0; fn < 4; ++fn) {
                acc[fm][fn] = __builtin_amdgcn_mfma_f32_16x16x32_f16(
                    af[fm][0], bq[fn], acc[fm][fn], 0, 0, 0);
                acc[fm][fn] = __builtin_amdgcn_mfma_f32_16x16x32_f16(
                    af[fm][1], bq[fn], acc[fm][fn], 0, 0, 0);
            }
    }

    #pragma unroll
    for (int fm = 0; fm < 4; ++fm)
        #pragma unroll
        for (int fn = 0; fn < 4; ++fn) {
            int col = col0 + wc * 64 + fn * 16 + l15;
            #pragma unroll
            for (int r = 0; r < 4; ++r) {
                int row = row0 + wr * 64 + fm * 16 + l4 * 4 + r;
                if (row < M) {
                    if (cb < 2)
                        xlh[(size_t)row * NCH + col] = __float2half_rn(acc[fm][fn][r]);
                    else
                        xr[(size_t)row * NCH + col] = acc[fm][fn][r];
                }
            }
        }
}

// ---------------------------------------------------------------------------
// GAT aggregation (FROZEN structure): persistent grid-stride waves,
// half-wave pair layout, packed-fp16 dot. lane = 32*el + l,
// channels [8l,8l+8); heads l 0..15 / 16..31.
// Grid: 1667 blocks -> 6668 waves x exactly 3 nodes (drain-tail balance).
// ---------------------------------------------------------------------------
static __device__ __forceinline__ float edge_dot(
        const uint4& r, const half2_t* xrh, const half2_t* atth) {
    const half2_t zh = (half2_t){(_Float16)0.f, (_Float16)0.f};
    const half2_t ch = (half2_t){(_Float16)LEAKY, (_Float16)LEAKY};
    float p = 0.f;
    #pragma unroll
    for (int q = 0; q < 4; ++q) {
        unsigned u = (&r.x)[q];
        half2_t t = u2h2(u) + xrh[q];
        half2_t m = __builtin_elementwise_max(t, zh) +
                    ch * __builtin_elementwise_min(t, zh);
        p = __builtin_amdgcn_fdot2(m, atth[q], p, false);
    }
    return p;
}

template <int LAST>
__global__ __launch_bounds__(256) void gat_agg8(
        const __half* __restrict__ xlh, const float* __restrict__ xr,
        const float* __restrict__ att, const float* __restrict__ bias,
        const int* __restrict__ offsets, const int* __restrict__ csr_src,
        __half* __restrict__ hhi, __half* __restrict__ hlo,
        const float* __restrict__ Wout, const float* __restrict__ bout,
        float* __restrict__ out, int nNodes) {
    int wid  = threadIdx.x >> 6;
    int lane = threadIdx.x & 63;
    int el = lane >> 5;
    int l  = lane & 31;
    int c0 = l * 8;

    half2_t atth[4];
    {
        float a8[8];
        *(float4*)&a8[0] = *(const float4*)&att[c0];
        *(float4*)&a8[4] = *(const float4*)&att[c0 + 4];
        #pragma unroll
        for (int q = 0; q < 4; ++q)
            atth[q] = (half2_t){(_Float16)a8[2 * q], (_Float16)a8[2 * q + 1]};
    }

    int stride = gridDim.x << 2;
    for (int node0 = (blockIdx.x << 2) + wid; node0 < nNodes; node0 += stride) {
        int node = __builtin_amdgcn_readfirstlane(node0);
        half2_t xrh[4];
        {
            float x8[8];
            *(float4*)&x8[0] = *(const float4*)&xr[(size_t)node * NCH + c0];
            *(float4*)&x8[4] = *(const float4*)&xr[(size_t)node * NCH + c0 + 4];
            #pragma unroll
            for (int q = 0; q < 4; ++q)
                xrh[q] = (half2_t){(_Float16)x8[2 * q], (_Float16)x8[2 * q + 1]};
        }

        int begin = offsets[node], end = offsets[node + 1];
        float denom = 0.f;
        float acc8[8];
        #pragma unroll
        for (int c = 0; c < 8; ++c) acc8[c] = 0.f;

        for (int j = begin; j < end; j += 4) {
            int j1 = j + 1 < end ? j + 1 : end - 1;
            int j2 = j + 2 < end ? j + 2 : end - 1;
            int j3 = j + 3 < end ? j + 3 : end - 1;
            int i0 = csr_src[j];
            int i1 = csr_src[j1];
            int i2 = csr_src[j2];
            int i3 = csr_src[j3];
            int sA = el ? i1 : i0;
            int sB = el ? i3 : i2;
            uint4 rA = *(const uint4*)&xlh[(size_t)sA * NCH + c0];
            uint4 rB = *(const uint4*)&xlh[(size_t)sB * NCH + c0];

            float pA = edge_dot(rA, xrh, atth);
            float pB = edge_dot(rB, xrh, atth);
            #pragma unroll
            for (int off = 1; off < 16; off <<= 1) {
                pA += __shfl_xor(pA, off);
                pB += __shfl_xor(pB, off);
            }
            float exA = (j + el < end)     ? __expf(pA) : 0.f;
            float exB = (j + 2 + el < end) ? __expf(pB) : 0.f;
            denom += exA + exB;
            #pragma unroll
            for (int q = 0; q < 4; ++q) {
                float2 fa = __half22float2(*(const __half2*)&(&rA.x)[q]);
                float2 fb = __half22float2(*(const __half2*)&(&rB.x)[q]);
                acc8[2 * q]     = fmaf(exA, fa.x, acc8[2 * q]);
                acc8[2 * q + 1] = fmaf(exA, fa.y, acc8[2 * q + 1]);
                acc8[2 * q]     = fmaf(exB, fb.x, acc8[2 * q]);
                acc8[2 * q + 1] = fmaf(exB, fb.y, acc8[2 * q + 1]);
            }
        }

        // combine edge-halves
        #pragma unroll
        for (int c = 0; c < 8; ++c) acc8[c] += __shfl_xor(acc8[c], 32);
        denom += __shfl_xor(denom, 32);
        float rd = 1.0f / denom;

        float o8[8], bi8[8];
        *(float4*)&bi8[0] = *(const float4*)&bias[c0];
        *(float4*)&bi8[4] = *(const float4*)&bias[c0 + 4];
        #pragma unroll
        for (int c = 0; c < 8; ++c)
            o8[c] = fmaxf(fmaf(acc8[c], rd, bi8[c]), 0.f);

        if (!LAST) {
            if (el == 0) {
                ushort h8[8], lo8[8];
                #pragma unroll
                for (int c = 0; c < 8; ++c) {
                    __half h = __float2half_rn(o8[c]);
                    h8[c]  = __half_as_ushort(h);
                    lo8[c] = __half_as_ushort(__float2half_rn(o8[c] - __half2float(h)));
                }
                *(uint4*)&hhi[(size_t)node * NCH + c0] = *(uint4*)&h8[0];
                *(uint4*)&hlo[(size_t)node * NCH + c0] = *(uint4*)&lo8[0];
            }
        } else {
            float p0 = 0.f, p1 = 0.f, p2 = 0.f, p3 = 0.f;
            #pragma unroll
            for (int c = 0; c < 8; ++c) {
                float4 w4 = *(const float4*)&Wout[(size_t)(c0 + c) * 4];
                p0 = fmaf(o8[c], w4.x, p0);
                p1 = fmaf(o8[c], w4.y, p1);
                p2 = fmaf(o8[c], w4.z, p2);
                p3 = fmaf(o8[c], w4.w, p3);
            }
            #pragma unroll
            for (int off = 1; off < 32; off <<= 1) {
                p0 += __shfl_xor(p0, off);
                p1 += __shfl_xor(p1, off);
                p2 += __shfl_xor(p2, off);
                p3 += __shfl_xor(p3, off);
            }
            if (lane == 0) {
                float4 r;
                r.x = p0 + bout[0]; r.y = p1 + bout[1];
                r.z = p2 + bout[2]; r.w = p3 + bout[3];
                *(float4*)&out[(size_t)node * 4] = r;
            }
        }
    }
}

// ---------------------------------------------------------------------------
extern "C" void kernel_launch(void* const* d_in, const int* in_sizes, int n_in,
                              void* d_out, int out_size, void* d_ws, size_t ws_size,
                              hipStream_t stream) {
    const float* x  = (const float*)d_in[0];
    const int*   ei = (const int*)d_in[1];
    const float* Wl[3]  = {(const float*)d_in[2], (const float*)d_in[6],  (const float*)d_in[10]};
    const float* Wr[3]  = {(const float*)d_in[3], (const float*)d_in[7],  (const float*)d_in[11]};
    const float* att[3] = {(const float*)d_in[4], (const float*)d_in[8],  (const float*)d_in[12]};
    const float* bb[3]  = {(const float*)d_in[5], (const float*)d_in[9],  (const float*)d_in[13]};
    const float* Wout = (const float*)d_in[14];
    const float* bout = (const float*)d_in[15];

    int Nn   = in_sizes[0] / NCH;       // 20000
    int E    = in_sizes[1] / 2;         // 320000

    size_t NEf = (size_t)Nn * NCH;
    __half* xlh  = (__half*)d_ws;                  // NEf
    float*  xr   = (float*)(xlh + NEf);            // NEf
    __half* bAhi = (__half*)(xr + NEf);            // NEf
    __half* bAlo = bAhi + NEf;
    __half* bBhi = bAlo + NEf;
    __half* bBlo = bBhi + NEf;
    __half* wt   = bBlo + NEf;                     // 6 * 65536
    int*   counts  = (int*)(wt + 6 * 65536);
    int*   offsets = counts + Nn;
    int*   cursor  = offsets + (Nn + 1);
    int*   csr_src = cursor + Nn;

    // wsplit first: transposes weights AND zeroes counts (saves a dispatch)
    WPtrs wp = {{Wl[0], Wr[0], Wl[1], Wr[1], Wl[2], Wr[2]}};
    wsplit_kernel<<<dim3(8, 8, 6), dim3(32, 32), 0, stream>>>(wp, wt, counts, Nn);

    int vthreads = (E >> 2) + Nn;                  // vectorized edges + self loops
    int vblocks  = (vthreads + 255) / 256;
    count_kernel<<<vblocks, 256, 0, stream>>>(ei, E, Nn, counts);
    scan_kernel<<<1, 1024, 0, stream>>>(counts, offsets, cursor, Nn);
    scatter_kernel<<<vblocks, 256, 0, stream>>>(ei, E, Nn, cursor, csr_src);

    int nrt = (Nn + 127) / 128;                    // 157 row tiles
    int prt = ((nrt + 7) / 8) * 8;                 // padded to 8
    int gblocks = prt * 4;                         // 640
    int nblocks = (Nn + 11) / 12;                  // 1667 -> 6668 waves x 3 nodes
    if (nblocks > (Nn + 3) / 4) nblocks = (Nn + 3) / 4;

    // layer 1: A = x (fp32, split in-register)
    dual_gemm_mfma<1><<<gblocks, 256, 0, stream>>>(x, nullptr, nullptr,
                                                   wt, xlh, xr, Nn);
    gat_agg8<0><<<nblocks, 256, 0, stream>>>(xlh, xr, att[0], bb[0],
        offsets, csr_src, bAhi, bAlo, nullptr, nullptr, nullptr, Nn);
    // layer 2: A = bufA (fp16 hi/lo)
    dual_gemm_mfma<0><<<gblocks, 256, 0, stream>>>(nullptr, bAhi, bAlo,
                                                   wt + 2 * 65536, xlh, xr, Nn);
    gat_agg8<0><<<nblocks, 256, 0, stream>>>(xlh, xr, att[1], bb[1],
        offsets, csr_src, bBhi, bBlo, nullptr, nullptr, nullptr, Nn);
    // layer 3: A = bufB, fused output projection
    dual_gemm_mfma<0><<<gblocks, 256, 0, stream>>>(nullptr, bBhi, bBlo,
                                                   wt + 4 * 65536, xlh, xr, Nn);
    gat_agg8<1><<<nblocks, 256, 0, stream>>>(xlh, xr, att[2], bb[2],
        offsets, csr_src, nullptr, nullptr, Wout, bout, (float*)d_out, Nn);
}

// Round 15
// 210.890 us; speedup vs baseline: 1.0378x; 1.0378x over previous
//
#include <hip/hip_runtime.h>
#include <hip/hip_bf16.h>
#include <hip/hip_fp16.h>
#include <math.h>

// N=20000, E=320000, layers: [N,256]@[256,256] GEMMs, HEADS=2, HID=128.
#define NCH 256
#define LEAKY 0.2f

typedef __attribute__((ext_vector_type(8))) _Float16 half8_t;  // 4 VGPRs
typedef __attribute__((ext_vector_type(2))) _Float16 half2_t;
typedef __attribute__((ext_vector_type(4))) float f32x4;       // MFMA C/D

static __device__ __forceinline__ half2_t u2h2(unsigned u) {
    return __builtin_bit_cast(half2_t, u);
}

// pack 8 fp32 -> fp16 hi + fp16 lo (hi+lo covers 22 mantissa bits)
static __device__ __forceinline__ void f32_to_hl8(const float4 a, const float4 b,
                                                  uint4& h, uint4& l) {
    float f[8] = {a.x, a.y, a.z, a.w, b.x, b.y, b.z, b.w};
    unsigned hs[8], ls[8];
    #pragma unroll
    for (int c = 0; c < 8; ++c) {
        __half hh = __float2half_rn(f[c]);
        hs[c] = __half_as_ushort(hh);
        ls[c] = __half_as_ushort(__float2half_rn(f[c] - __half2float(hh)));
    }
    h = make_uint4(hs[0] | (hs[1] << 16), hs[2] | (hs[3] << 16),
                   hs[4] | (hs[5] << 16), hs[6] | (hs[7] << 16));
    l = make_uint4(ls[0] | (ls[1] << 16), ls[2] | (ls[3] << 16),
                   ls[4] | (ls[5] << 16), ls[6] | (ls[7] << 16));
}

// ---------------------------------------------------------------------------
// CSR build: counts (int4-vectorized; counts zeroed by wsplit_kernel which
// runs first on the serial stream) -> scan (4 elem/thread) -> scatter.
// ---------------------------------------------------------------------------
__global__ void count_kernel(const int* __restrict__ ei, int E, int n,
                             int* __restrict__ counts) {
    int tid = blockIdx.x * 256 + threadIdx.x;
    int E4 = E >> 2;                    // E divisible by 4 here (320000)
    if (tid < E4) {
        int4 d = ((const int4*)(ei + E))[tid];
        atomicAdd(&counts[d.x], 1);
        atomicAdd(&counts[d.y], 1);
        atomicAdd(&counts[d.z], 1);
        atomicAdd(&counts[d.w], 1);
    } else {
        int s = tid - E4;               // self loops
        if (s < n) atomicAdd(&counts[s], 1);
    }
}

__global__ void scan_kernel(const int* __restrict__ counts,
                            int* __restrict__ offsets,
                            int* __restrict__ cursor, int n) {
    __shared__ int wsum[16];
    int tid  = threadIdx.x;          // 1024 threads = 16 waves, 4 elem/thread
    int lane = tid & 63, w = tid >> 6;
    int carry = 0;
    for (int base = 0; base < n; base += 4096) {
        int i0 = base + tid * 4;
        int v0 = 0, v1 = 0, v2 = 0, v3 = 0;
        if (i0 + 3 < n) {
            int4 v = *(const int4*)&counts[i0];
            v0 = v.x; v1 = v.y; v2 = v.z; v3 = v.w;
        } else if (i0 < n) {
            v0 = counts[i0];
            if (i0 + 1 < n) v1 = counts[i0 + 1];
            if (i0 + 2 < n) v2 = counts[i0 + 2];
        }
        int c1 = v0 + v1, c2 = c1 + v2, c3 = c2 + v3;
        int tsum = c3;
        int incl = tsum;
        #pragma unroll
        for (int off = 1; off < 64; off <<= 1) {
            int t2 = __shfl_up(incl, off, 64);
            if (lane >= off) incl += t2;
        }
        if (lane == 63) wsum[w] = incl;
        __syncthreads();
        if (w == 0 && lane < 16) {
            int s = wsum[lane];
            #pragma unroll
            for (int off = 1; off < 16; off <<= 1) {
                int t2 = __shfl_up(s, off, 64);
                if (lane >= off) s += t2;
            }
            wsum[lane] = s;
        }
        __syncthreads();
        int wpre = (w == 0) ? 0 : wsum[w - 1];
        int excl = carry + wpre + incl - tsum;
        if (i0 + 3 < n) {
            int4 o = make_int4(excl, excl + v0, excl + c1, excl + c2);
            *(int4*)&offsets[i0] = o;
            *(int4*)&cursor[i0]  = o;
        } else if (i0 < n) {
            offsets[i0] = excl;           cursor[i0] = excl;
            if (i0 + 1 < n) { offsets[i0 + 1] = excl + v0; cursor[i0 + 1] = excl + v0; }
            if (i0 + 2 < n) { offsets[i0 + 2] = excl + c1; cursor[i0 + 2] = excl + c1; }
        }
        carry += wsum[15];
        __syncthreads();
    }
    if (tid == 0) offsets[n] = carry;
}

__global__ void scatter_kernel(const int* __restrict__ ei, int E, int n,
                               int* __restrict__ cursor,
                               int* __restrict__ csr_src) {
    int tid = blockIdx.x * 256 + threadIdx.x;
    int E4 = E >> 2;
    if (tid < E4) {
        int4 s = ((const int4*)ei)[tid];
        int4 d = ((const int4*)(ei + E))[tid];
        csr_src[atomicAdd(&cursor[d.x], 1)] = s.x;
        csr_src[atomicAdd(&cursor[d.y], 1)] = s.y;
        csr_src[atomicAdd(&cursor[d.z], 1)] = s.z;
        csr_src[atomicAdd(&cursor[d.w], 1)] = s.w;
    } else {
        int i = tid - E4;               // self loops
        if (i < n) csr_src[atomicAdd(&cursor[i], 1)] = i;
    }
}

// ---------------------------------------------------------------------------
// Weight transpose: W[256,256] (k-major) -> Wt[256,256] (n-major) fp16.
// Also zeroes counts[] (runs FIRST; stream order makes this safe and saves
// a dedicated zero dispatch).
// ---------------------------------------------------------------------------
struct WPtrs { const float* w[6]; };
__global__ __launch_bounds__(1024) void wsplit_kernel(WPtrs p,
        __half* __restrict__ wt, int* __restrict__ counts, int n) {
    int gid = ((blockIdx.z * gridDim.y + blockIdx.y) * gridDim.x + blockIdx.x) * 1024
              + threadIdx.y * 32 + threadIdx.x;
    if (gid < n) counts[gid] = 0;

    __shared__ float tile[32][33];
    int m = blockIdx.z;
    const float* W = p.w[m];
    size_t base = (size_t)m * 65536;
    int k = blockIdx.y * 32 + threadIdx.y;
    int nn = blockIdx.x * 32 + threadIdx.x;
    tile[threadIdx.y][threadIdx.x] = W[k * NCH + nn];
    __syncthreads();
    int on = blockIdx.x * 32 + threadIdx.y;
    int ok = blockIdx.y * 32 + threadIdx.x;
    wt[base + (size_t)on * NCH + ok] = __float2half_rn(tile[threadIdx.x][threadIdx.y]);
}

// ---------------------------------------------------------------------------
// MFMA dual GEMM, fp16 2-product split: C = Ahi*B + Alo*B (B single fp16).
// AF32: A is fp32 (layer 1), hi/lo split in-register during staging.
// Flat grid with L2-reuse swizzle (stripes of 32 = 8 row-tiles x 4 cbs).
// xl written fp16 (gather side), xr fp32.  (R11/R13-proven version.)
// ---------------------------------------------------------------------------
#define LDK 40
template <int AF32>
__global__ __launch_bounds__(256) void dual_gemm_mfma(
        const float* __restrict__ Af,
        const __half* __restrict__ Ahi, const __half* __restrict__ Alo,
        const __half* __restrict__ Bt,
        __half* __restrict__ xlh, float* __restrict__ xr, int M) {
    __shared__ ushort As[2][128 * LDK];
    __shared__ ushort Bs[128 * LDK];
    int b = blockIdx.x;
    int stripe = b >> 5;
    int wslot  = b & 31;
    int rt = (stripe << 3) + (wslot & 7);
    int cb = wslot >> 3;
    int row0 = rt * 128;
    if (row0 >= M) return;
    const __half* Bm = Bt + (size_t)(cb >> 1) * 65536;
    int col0 = (cb & 1) * 128;
    int t = threadIdx.x;
    int lane = t & 63, w = t >> 6;
    int wr = w >> 1, wc = w & 1;
    int l15 = lane & 15, l4 = lane >> 4;

    f32x4 acc[4][4];
    #pragma unroll
    for (int i = 0; i < 4; ++i)
        #pragma unroll
        for (int j = 0; j < 4; ++j) acc[i][j] = (f32x4){0.f, 0.f, 0.f, 0.f};

    int r0 = t >> 2,          q0 = (t & 3) * 8;
    int r1 = (t + 256) >> 2,  q1 = ((t + 256) & 3) * 8;

    for (int k0 = 0; k0 < 256; k0 += 32) {
        uint4 z = make_uint4(0, 0, 0, 0);
        uint4 a0h = z, a0l = z, a1h = z, a1l = z;
        if (row0 + r0 < M) {
            if (AF32) {
                float4 fa = *(const float4*)&Af[(size_t)(row0 + r0) * NCH + k0 + q0];
                float4 fb = *(const float4*)&Af[(size_t)(row0 + r0) * NCH + k0 + q0 + 4];
                f32_to_hl8(fa, fb, a0h, a0l);
            } else {
                a0h = *(const uint4*)&Ahi[(size_t)(row0 + r0) * NCH + k0 + q0];
                a0l = *(const uint4*)&Alo[(size_t)(row0 + r0) * NCH + k0 + q0];
            }
        }
        if (row0 + r1 < M) {
            if (AF32) {
                float4 fa = *(const float4*)&Af[(size_t)(row0 + r1) * NCH + k0 + q1];
                float4 fb = *(const float4*)&Af[(size_t)(row0 + r1) * NCH + k0 + q1 + 4];
                f32_to_hl8(fa, fb, a1h, a1l);
            } else {
                a1h = *(const uint4*)&Ahi[(size_t)(row0 + r1) * NCH + k0 + q1];
                a1l = *(const uint4*)&Alo[(size_t)(row0 + r1) * NCH + k0 + q1];
            }
        }
        uint4 b0 = *(const uint4*)&Bm[(size_t)(col0 + r0) * NCH + k0 + q0];
        uint4 b1 = *(const uint4*)&Bm[(size_t)(col0 + r1) * NCH + k0 + q1];
        __syncthreads();
        *(uint4*)&As[0][r0 * LDK + q0] = a0h;
        *(uint4*)&As[1][r0 * LDK + q0] = a0l;
        *(uint4*)&As[0][r1 * LDK + q1] = a1h;
        *(uint4*)&As[1][r1 * LDK + q1] = a1l;
        *(uint4*)&Bs[r0 * LDK + q0] = b0;
        *(uint4*)&Bs[r1 * LDK + q1] = b1;
        __syncthreads();

        half8_t af[4][2], bq[4];
        #pragma unroll
        for (int fm = 0; fm < 4; ++fm) {
            int addr = (wr * 64 + fm * 16 + l15) * LDK + l4 * 8;
            af[fm][0] = *(const half8_t*)&As[0][addr];
            af[fm][1] = *(const half8_t*)&As[1][addr];
        }
        #pragma unroll
        for (int fn = 0; fn < 4; ++fn) {
            int addr = (wc * 64 + fn * 16 + l15) * LDK + l4 * 8;
            bq[fn] = *(const half8_t*)&Bs[addr];
        }
        #pragma unroll
        for (int fm = 0; fm < 4; ++fm)
            #pragma unroll
            for (int fn = 0; fn < 4; ++fn) {
                acc[fm][fn] = __builtin_amdgcn_mfma_f32_16x16x32_f16(
                    af[fm][0], bq[fn], acc[fm][fn], 0, 0, 0);
                acc[fm][fn] = __builtin_amdgcn_mfma_f32_16x16x32_f16(
                    af[fm][1], bq[fn], acc[fm][fn], 0, 0, 0);
            }
    }

    #pragma unroll
    for (int fm = 0; fm < 4; ++fm)
        #pragma unroll
        for (int fn = 0; fn < 4; ++fn) {
            int col = col0 + wc * 64 + fn * 16 + l15;
            #pragma unroll
            for (int r = 0; r < 4; ++r) {
                int row = row0 + wr * 64 + fm * 16 + l4 * 4 + r;
                if (row < M) {
                    if (cb < 2)
                        xlh[(size_t)row * NCH + col] = __float2half_rn(acc[fm][fn][r]);
                    else
                        xr[(size_t)row * NCH + col] = acc[fm][fn][r];
                }
            }
        }
}

// ---------------------------------------------------------------------------
// GAT aggregation (FROZEN structure): persistent grid-stride waves,
// half-wave pair layout, packed-fp16 dot. lane = 32*el + l,
// channels [8l,8l+8); heads l 0..15 / 16..31.
// Grid: 2048 blocks (R13-proven: full residency at 8 blocks/CU, 52 VGPR).
// ---------------------------------------------------------------------------
static __device__ __forceinline__ float edge_dot(
        const uint4& r, const half2_t* xrh, const half2_t* atth) {
    const half2_t zh = (half2_t){(_Float16)0.f, (_Float16)0.f};
    const half2_t ch = (half2_t){(_Float16)LEAKY, (_Float16)LEAKY};
    float p = 0.f;
    #pragma unroll
    for (int q = 0; q < 4; ++q) {
        unsigned u = (&r.x)[q];
        half2_t t = u2h2(u) + xrh[q];
        half2_t m = __builtin_elementwise_max(t, zh) +
                    ch * __builtin_elementwise_min(t, zh);
        p = __builtin_amdgcn_fdot2(m, atth[q], p, false);
    }
    return p;
}

template <int LAST>
__global__ __launch_bounds__(256) void gat_agg8(
        const __half* __restrict__ xlh, const float* __restrict__ xr,
        const float* __restrict__ att, const float* __restrict__ bias,
        const int* __restrict__ offsets, const int* __restrict__ csr_src,
        __half* __restrict__ hhi, __half* __restrict__ hlo,
        const float* __restrict__ Wout, const float* __restrict__ bout,
        float* __restrict__ out, int nNodes) {
    int wid  = threadIdx.x >> 6;
    int lane = threadIdx.x & 63;
    int el = lane >> 5;
    int l  = lane & 31;
    int c0 = l * 8;

    half2_t atth[4];
    {
        float a8[8];
        *(float4*)&a8[0] = *(const float4*)&att[c0];
        *(float4*)&a8[4] = *(const float4*)&att[c0 + 4];
        #pragma unroll
        for (int q = 0; q < 4; ++q)
            atth[q] = (half2_t){(_Float16)a8[2 * q], (_Float16)a8[2 * q + 1]};
    }

    int stride = gridDim.x << 2;
    for (int node0 = (blockIdx.x << 2) + wid; node0 < nNodes; node0 += stride) {
        int node = __builtin_amdgcn_readfirstlane(node0);
        half2_t xrh[4];
        {
            float x8[8];
            *(float4*)&x8[0] = *(const float4*)&xr[(size_t)node * NCH + c0];
            *(float4*)&x8[4] = *(const float4*)&xr[(size_t)node * NCH + c0 + 4];
            #pragma unroll
            for (int q = 0; q < 4; ++q)
                xrh[q] = (half2_t){(_Float16)x8[2 * q], (_Float16)x8[2 * q + 1]};
        }

        int begin = offsets[node], end = offsets[node + 1];
        float denom = 0.f;
        float acc8[8];
        #pragma unroll
        for (int c = 0; c < 8; ++c) acc8[c] = 0.f;

        for (int j = begin; j < end; j += 4) {
            int j1 = j + 1 < end ? j + 1 : end - 1;
            int j2 = j + 2 < end ? j + 2 : end - 1;
            int j3 = j + 3 < end ? j + 3 : end - 1;
            int i0 = csr_src[j];
            int i1 = csr_src[j1];
            int i2 = csr_src[j2];
            int i3 = csr_src[j3];
            int sA = el ? i1 : i0;
            int sB = el ? i3 : i2;
            uint4 rA = *(const uint4*)&xlh[(size_t)sA * NCH + c0];
            uint4 rB = *(const uint4*)&xlh[(size_t)sB * NCH + c0];

            float pA = edge_dot(rA, xrh, atth);
            float pB = edge_dot(rB, xrh, atth);
            #pragma unroll
            for (int off = 1; off < 16; off <<= 1) {
                pA += __shfl_xor(pA, off);
                pB += __shfl_xor(pB, off);
            }
            float exA = (j + el < end)     ? __expf(pA) : 0.f;
            float exB = (j + 2 + el < end) ? __expf(pB) : 0.f;
            denom += exA + exB;
            #pragma unroll
            for (int q = 0; q < 4; ++q) {
                float2 fa = __half22float2(*(const __half2*)&(&rA.x)[q]);
                float2 fb = __half22float2(*(const __half2*)&(&rB.x)[q]);
                acc8[2 * q]     = fmaf(exA, fa.x, acc8[2 * q]);
                acc8[2 * q + 1] = fmaf(exA, fa.y, acc8[2 * q + 1]);
                acc8[2 * q]     = fmaf(exB, fb.x, acc8[2 * q]);
                acc8[2 * q + 1] = fmaf(exB, fb.y, acc8[2 * q + 1]);
            }
        }

        // combine edge-halves
        #pragma unroll
        for (int c = 0; c < 8; ++c) acc8[c] += __shfl_xor(acc8[c], 32);
        denom += __shfl_xor(denom, 32);
        float rd = 1.0f / denom;

        float o8[8], bi8[8];
        *(float4*)&bi8[0] = *(const float4*)&bias[c0];
        *(float4*)&bi8[4] = *(const float4*)&bias[c0 + 4];
        #pragma unroll
        for (int c = 0; c < 8; ++c)
            o8[c] = fmaxf(fmaf(acc8[c], rd, bi8[c]), 0.f);

        if (!LAST) {
            if (el == 0) {
                ushort h8[8], lo8[8];
                #pragma unroll
                for (int c = 0; c < 8; ++c) {
                    __half h = __float2half_rn(o8[c]);
                    h8[c]  = __half_as_ushort(h);
                    lo8[c] = __half_as_ushort(__float2half_rn(o8[c] - __half2float(h)));
                }
                *(uint4*)&hhi[(size_t)node * NCH + c0] = *(uint4*)&h8[0];
                *(uint4*)&hlo[(size_t)node * NCH + c0] = *(uint4*)&lo8[0];
            }
        } else {
            float p0 = 0.f, p1 = 0.f, p2 = 0.f, p3 = 0.f;
            #pragma unroll
            for (int c = 0; c < 8; ++c) {
                float4 w4 = *(const float4*)&Wout[(size_t)(c0 + c) * 4];
                p0 = fmaf(o8[c], w4.x, p0);
                p1 = fmaf(o8[c], w4.y, p1);
                p2 = fmaf(o8[c], w4.z, p2);
                p3 = fmaf(o8[c], w4.w, p3);
            }
            #pragma unroll
            for (int off = 1; off < 32; off <<= 1) {
                p0 += __shfl_xor(p0, off);
                p1 += __shfl_xor(p1, off);
                p2 += __shfl_xor(p2, off);
                p3 += __shfl_xor(p3, off);
            }
            if (lane == 0) {
                float4 r;
                r.x = p0 + bout[0]; r.y = p1 + bout[1];
                r.z = p2 + bout[2]; r.w = p3 + bout[3];
                *(float4*)&out[(size_t)node * 4] = r;
            }
        }
    }
}

// ---------------------------------------------------------------------------
extern "C" void kernel_launch(void* const* d_in, const int* in_sizes, int n_in,
                              void* d_out, int out_size, void* d_ws, size_t ws_size,
                              hipStream_t stream) {
    const float* x  = (const float*)d_in[0];
    const int*   ei = (const int*)d_in[1];
    const float* Wl[3]  = {(const float*)d_in[2], (const float*)d_in[6],  (const float*)d_in[10]};
    const float* Wr[3]  = {(const float*)d_in[3], (const float*)d_in[7],  (const float*)d_in[11]};
    const float* att[3] = {(const float*)d_in[4], (const float*)d_in[8],  (const float*)d_in[12]};
    const float* bb[3]  = {(const float*)d_in[5], (const float*)d_in[9],  (const float*)d_in[13]};
    const float* Wout = (const float*)d_in[14];
    const float* bout = (const float*)d_in[15];

    int Nn   = in_sizes[0] / NCH;       // 20000
    int E    = in_sizes[1] / 2;         // 320000

    size_t NEf = (size_t)Nn * NCH;
    __half* xlh  = (__half*)d_ws;                  // NEf
    float*  xr   = (float*)(xlh + NEf);            // NEf
    __half* bAhi = (__half*)(xr + NEf);            // NEf
    __half* bAlo = bAhi + NEf;
    __half* bBhi = bAlo + NEf;
    __half* bBlo = bBhi + NEf;
    __half* wt   = bBlo + NEf;                     // 6 * 65536
    int*   counts  = (int*)(wt + 6 * 65536);
    int*   offsets = counts + Nn;
    int*   cursor  = offsets + (Nn + 1);
    int*   csr_src = cursor + Nn;

    // wsplit first: transposes weights AND zeroes counts (saves a dispatch)
    WPtrs wp = {{Wl[0], Wr[0], Wl[1], Wr[1], Wl[2], Wr[2]}};
    wsplit_kernel<<<dim3(8, 8, 6), dim3(32, 32), 0, stream>>>(wp, wt, counts, Nn);

    int vthreads = (E >> 2) + Nn;                  // vectorized edges + self loops
    int vblocks  = (vthreads + 255) / 256;
    count_kernel<<<vblocks, 256, 0, stream>>>(ei, E, Nn, counts);
    scan_kernel<<<1, 1024, 0, stream>>>(counts, offsets, cursor, Nn);
    scatter_kernel<<<vblocks, 256, 0, stream>>>(ei, E, Nn, cursor, csr_src);

    int nrt = (Nn + 127) / 128;                    // 157 row tiles
    int prt = ((nrt + 7) / 8) * 8;                 // padded to 8
    int gblocks = prt * 4;                         // 640
    int nblocks = 2048;                            // R13-proven gat grid
    if (nblocks > (Nn + 3) / 4) nblocks = (Nn + 3) / 4;

    // layer 1: A = x (fp32, split in-register)
    dual_gemm_mfma<1><<<gblocks, 256, 0, stream>>>(x, nullptr, nullptr,
                                                   wt, xlh, xr, Nn);
    gat_agg8<0><<<nblocks, 256, 0, stream>>>(xlh, xr, att[0], bb[0],
        offsets, csr_src, bAhi, bAlo, nullptr, nullptr, nullptr, Nn);
    // layer 2: A = bufA (fp16 hi/lo)
    dual_gemm_mfma<0><<<gblocks, 256, 0, stream>>>(nullptr, bAhi, bAlo,
                                                   wt + 2 * 65536, xlh, xr, Nn);
    gat_agg8<0><<<nblocks, 256, 0, stream>>>(xlh, xr, att[1], bb[1],
        offsets, csr_src, bBhi, bBlo, nullptr, nullptr, nullptr, Nn);
    // layer 3: A = bufB, fused output projection
    dual_gemm_mfma<0><<<gblocks, 256, 0, stream>>>(nullptr, bBhi, bBlo,
                                                   wt + 4 * 65536, xlh, xr, Nn);
    gat_agg8<1><<<nblocks, 256, 0, stream>>>(xlh, xr, att[2], bb[2],
        offsets, csr_src, nullptr, nullptr, Wout, bout, (float*)d_out, Nn);
}

// Round 16
// 204.138 us; speedup vs baseline: 1.0722x; 1.0331x over previous
//
#include <hip/hip_runtime.h>
#include <hip/hip_bf16.h>
#include <hip/hip_fp16.h>
#include <math.h>

// N=20000, E=320000, layers: [N,256]@[256,256] GEMMs, HEADS=2, HID=128.
#define NCH 256
#define LEAKY 0.2f

typedef __attribute__((ext_vector_type(8))) _Float16 half8_t;  // 4 VGPRs
typedef __attribute__((ext_vector_type(2))) _Float16 half2_t;
typedef __attribute__((ext_vector_type(4))) float f32x4;       // MFMA C/D

static __device__ __forceinline__ half2_t u2h2(unsigned u) {
    return __builtin_bit_cast(half2_t, u);
}

// pack 8 fp32 -> fp16 hi + fp16 lo (hi+lo covers 22 mantissa bits)
static __device__ __forceinline__ void f32_to_hl8(const float4 a, const float4 b,
                                                  uint4& h, uint4& l) {
    float f[8] = {a.x, a.y, a.z, a.w, b.x, b.y, b.z, b.w};
    unsigned hs[8], ls[8];
    #pragma unroll
    for (int c = 0; c < 8; ++c) {
        __half hh = __float2half_rn(f[c]);
        hs[c] = __half_as_ushort(hh);
        ls[c] = __half_as_ushort(__float2half_rn(f[c] - __half2float(hh)));
    }
    h = make_uint4(hs[0] | (hs[1] << 16), hs[2] | (hs[3] << 16),
                   hs[4] | (hs[5] << 16), hs[6] | (hs[7] << 16));
    l = make_uint4(ls[0] | (ls[1] << 16), ls[2] | (ls[3] << 16),
                   ls[4] | (ls[5] << 16), ls[6] | (ls[7] << 16));
}

// ---------------------------------------------------------------------------
// CSR build: counts (int4-vectorized; counts zeroed by wsplit_kernel which
// runs first on the serial stream) -> scan (4 elem/thread) -> scatter.
// ---------------------------------------------------------------------------
__global__ void count_kernel(const int* __restrict__ ei, int E, int n,
                             int* __restrict__ counts) {
    int tid = blockIdx.x * 256 + threadIdx.x;
    int E4 = E >> 2;                    // E divisible by 4 here (320000)
    if (tid < E4) {
        int4 d = ((const int4*)(ei + E))[tid];
        atomicAdd(&counts[d.x], 1);
        atomicAdd(&counts[d.y], 1);
        atomicAdd(&counts[d.z], 1);
        atomicAdd(&counts[d.w], 1);
    } else {
        int s = tid - E4;               // self loops
        if (s < n) atomicAdd(&counts[s], 1);
    }
}

__global__ void scan_kernel(const int* __restrict__ counts,
                            int* __restrict__ offsets,
                            int* __restrict__ cursor, int n) {
    __shared__ int wsum[16];
    int tid  = threadIdx.x;          // 1024 threads = 16 waves, 4 elem/thread
    int lane = tid & 63, w = tid >> 6;
    int carry = 0;
    for (int base = 0; base < n; base += 4096) {
        int i0 = base + tid * 4;
        int v0 = 0, v1 = 0, v2 = 0, v3 = 0;
        if (i0 + 3 < n) {
            int4 v = *(const int4*)&counts[i0];
            v0 = v.x; v1 = v.y; v2 = v.z; v3 = v.w;
        } else if (i0 < n) {
            v0 = counts[i0];
            if (i0 + 1 < n) v1 = counts[i0 + 1];
            if (i0 + 2 < n) v2 = counts[i0 + 2];
        }
        int c1 = v0 + v1, c2 = c1 + v2, c3 = c2 + v3;
        int tsum = c3;
        int incl = tsum;
        #pragma unroll
        for (int off = 1; off < 64; off <<= 1) {
            int t2 = __shfl_up(incl, off, 64);
            if (lane >= off) incl += t2;
        }
        if (lane == 63) wsum[w] = incl;
        __syncthreads();
        if (w == 0 && lane < 16) {
            int s = wsum[lane];
            #pragma unroll
            for (int off = 1; off < 16; off <<= 1) {
                int t2 = __shfl_up(s, off, 64);
                if (lane >= off) s += t2;
            }
            wsum[lane] = s;
        }
        __syncthreads();
        int wpre = (w == 0) ? 0 : wsum[w - 1];
        int excl = carry + wpre + incl - tsum;
        if (i0 + 3 < n) {
            int4 o = make_int4(excl, excl + v0, excl + c1, excl + c2);
            *(int4*)&offsets[i0] = o;
            *(int4*)&cursor[i0]  = o;
        } else if (i0 < n) {
            offsets[i0] = excl;           cursor[i0] = excl;
            if (i0 + 1 < n) { offsets[i0 + 1] = excl + v0; cursor[i0 + 1] = excl + v0; }
            if (i0 + 2 < n) { offsets[i0 + 2] = excl + c1; cursor[i0 + 2] = excl + c1; }
        }
        carry += wsum[15];
        __syncthreads();
    }
    if (tid == 0) offsets[n] = carry;
}

__global__ void scatter_kernel(const int* __restrict__ ei, int E, int n,
                               int* __restrict__ cursor,
                               int* __restrict__ csr_src) {
    int tid = blockIdx.x * 256 + threadIdx.x;
    int E4 = E >> 2;
    if (tid < E4) {
        int4 s = ((const int4*)ei)[tid];
        int4 d = ((const int4*)(ei + E))[tid];
        csr_src[atomicAdd(&cursor[d.x], 1)] = s.x;
        csr_src[atomicAdd(&cursor[d.y], 1)] = s.y;
        csr_src[atomicAdd(&cursor[d.z], 1)] = s.z;
        csr_src[atomicAdd(&cursor[d.w], 1)] = s.w;
    } else {
        int i = tid - E4;               // self loops
        if (i < n) csr_src[atomicAdd(&cursor[i], 1)] = i;
    }
}

// ---------------------------------------------------------------------------
// Weight transpose: W[256,256] (k-major) -> Wt[256,256] (n-major) fp16.
// Also zeroes counts[] (runs FIRST; stream order makes this safe and saves
// a dedicated zero dispatch).
// ---------------------------------------------------------------------------
struct WPtrs { const float* w[6]; };
__global__ __launch_bounds__(1024) void wsplit_kernel(WPtrs p,
        __half* __restrict__ wt, int* __restrict__ counts, int n) {
    int gid = ((blockIdx.z * gridDim.y + blockIdx.y) * gridDim.x + blockIdx.x) * 1024
              + threadIdx.y * 32 + threadIdx.x;
    if (gid < n) counts[gid] = 0;

    __shared__ float tile[32][33];
    int m = blockIdx.z;
    const float* W = p.w[m];
    size_t base = (size_t)m * 65536;
    int k = blockIdx.y * 32 + threadIdx.y;
    int nn = blockIdx.x * 32 + threadIdx.x;
    tile[threadIdx.y][threadIdx.x] = W[k * NCH + nn];
    __syncthreads();
    int on = blockIdx.x * 32 + threadIdx.y;
    int ok = blockIdx.y * 32 + threadIdx.x;
    wt[base + (size_t)on * NCH + ok] = __float2half_rn(tile[threadIdx.x][threadIdx.y]);
}

// ---------------------------------------------------------------------------
// MFMA dual GEMM, fp16 2-product split: C = Ahi*B + Alo*B (B single fp16).
// AF32: A is fp32 (layer 1), hi/lo split in-register during staging.
// Flat grid with L2-reuse swizzle (stripes of 32 = 8 row-tiles x 4 cbs).
// BOTH xl and xr written fp16: gat's dot path truncates xr to fp16 anyway,
// so fp32-xr storage was pure wasted bandwidth (10.2MB write + read /layer).
// ---------------------------------------------------------------------------
#define LDK 40
template <int AF32>
__global__ __launch_bounds__(256) void dual_gemm_mfma(
        const float* __restrict__ Af,
        const __half* __restrict__ Ahi, const __half* __restrict__ Alo,
        const __half* __restrict__ Bt,
        __half* __restrict__ xlh, __half* __restrict__ xrh, int M) {
    __shared__ ushort As[2][128 * LDK];
    __shared__ ushort Bs[128 * LDK];
    int b = blockIdx.x;
    int stripe = b >> 5;
    int wslot  = b & 31;
    int rt = (stripe << 3) + (wslot & 7);
    int cb = wslot >> 3;
    int row0 = rt * 128;
    if (row0 >= M) return;
    const __half* Bm = Bt + (size_t)(cb >> 1) * 65536;
    int col0 = (cb & 1) * 128;
    int t = threadIdx.x;
    int lane = t & 63, w = t >> 6;
    int wr = w >> 1, wc = w & 1;
    int l15 = lane & 15, l4 = lane >> 4;

    f32x4 acc[4][4];
    #pragma unroll
    for (int i = 0; i < 4; ++i)
        #pragma unroll
        for (int j = 0; j < 4; ++j) acc[i][j] = (f32x4){0.f, 0.f, 0.f, 0.f};

    int r0 = t >> 2,          q0 = (t & 3) * 8;
    int r1 = (t + 256) >> 2,  q1 = ((t + 256) & 3) * 8;

    for (int k0 = 0; k0 < 256; k0 += 32) {
        uint4 z = make_uint4(0, 0, 0, 0);
        uint4 a0h = z, a0l = z, a1h = z, a1l = z;
        if (row0 + r0 < M) {
            if (AF32) {
                float4 fa = *(const float4*)&Af[(size_t)(row0 + r0) * NCH + k0 + q0];
                float4 fb = *(const float4*)&Af[(size_t)(row0 + r0) * NCH + k0 + q0 + 4];
                f32_to_hl8(fa, fb, a0h, a0l);
            } else {
                a0h = *(const uint4*)&Ahi[(size_t)(row0 + r0) * NCH + k0 + q0];
                a0l = *(const uint4*)&Alo[(size_t)(row0 + r0) * NCH + k0 + q0];
            }
        }
        if (row0 + r1 < M) {
            if (AF32) {
                float4 fa = *(const float4*)&Af[(size_t)(row0 + r1) * NCH + k0 + q1];
                float4 fb = *(const float4*)&Af[(size_t)(row0 + r1) * NCH + k0 + q1 + 4];
                f32_to_hl8(fa, fb, a1h, a1l);
            } else {
                a1h = *(const uint4*)&Ahi[(size_t)(row0 + r1) * NCH + k0 + q1];
                a1l = *(const uint4*)&Alo[(size_t)(row0 + r1) * NCH + k0 + q1];
            }
        }
        uint4 b0 = *(const uint4*)&Bm[(size_t)(col0 + r0) * NCH + k0 + q0];
        uint4 b1 = *(const uint4*)&Bm[(size_t)(col0 + r1) * NCH + k0 + q1];
        __syncthreads();
        *(uint4*)&As[0][r0 * LDK + q0] = a0h;
        *(uint4*)&As[1][r0 * LDK + q0] = a0l;
        *(uint4*)&As[0][r1 * LDK + q1] = a1h;
        *(uint4*)&As[1][r1 * LDK + q1] = a1l;
        *(uint4*)&Bs[r0 * LDK + q0] = b0;
        *(uint4*)&Bs[r1 * LDK + q1] = b1;
        __syncthreads();

        half8_t af[4][2], bq[4];
        #pragma unroll
        for (int fm = 0; fm < 4; ++fm) {
            int addr = (wr * 64 + fm * 16 + l15) * LDK + l4 * 8;
            af[fm][0] = *(const half8_t*)&As[0][addr];
            af[fm][1] = *(const half8_t*)&As[1][addr];
        }
        #pragma unroll
        for (int fn = 0; fn < 4; ++fn) {
            int addr = (wc * 64 + fn * 16 + l15) * LDK + l4 * 8;
            bq[fn] = *(const half8_t*)&Bs[addr];
        }
        #pragma unroll
        for (int fm = 0; fm < 4; ++fm)
            #pragma unroll
            for (int fn = 0; fn < 4; ++fn) {
                acc[fm][fn] = __builtin_amdgcn_mfma_f32_16x16x32_f16(
                    af[fm][0], bq[fn], acc[fm][fn], 0, 0, 0);
                acc[fm][fn] = __builtin_amdgcn_mfma_f32_16x16x32_f16(
                    af[fm][1], bq[fn], acc[fm][fn], 0, 0, 0);
            }
    }

    __half* Out = (cb < 2) ? xlh : xrh;
    #pragma unroll
    for (int fm = 0; fm < 4; ++fm)
        #pragma unroll
        for (int fn = 0; fn < 4; ++fn) {
            int col = col0 + wc * 64 + fn * 16 + l15;
            #pragma unroll
            for (int r = 0; r < 4; ++r) {
                int row = row0 + wr * 64 + fm * 16 + l4 * 4 + r;
                if (row < M)
                    Out[(size_t)row * NCH + col] = __float2half_rn(acc[fm][fn][r]);
            }
        }
}

// ---------------------------------------------------------------------------
// GAT aggregation (FROZEN structure): persistent grid-stride waves,
// half-wave pair layout, packed-fp16 dot. lane = 32*el + l,
// channels [8l,8l+8); heads l 0..15 / 16..31.
// Grid: 2048 blocks (proven: full residency at 8 blocks/CU, 52 VGPR).
// xr is now fp16 (bit-identical results: dot path always used fp16 xr).
// ---------------------------------------------------------------------------
static __device__ __forceinline__ float edge_dot(
        const uint4& r, const half2_t* xrh, const half2_t* atth) {
    const half2_t zh = (half2_t){(_Float16)0.f, (_Float16)0.f};
    const half2_t ch = (half2_t){(_Float16)LEAKY, (_Float16)LEAKY};
    float p = 0.f;
    #pragma unroll
    for (int q = 0; q < 4; ++q) {
        unsigned u = (&r.x)[q];
        half2_t t = u2h2(u) + xrh[q];
        half2_t m = __builtin_elementwise_max(t, zh) +
                    ch * __builtin_elementwise_min(t, zh);
        p = __builtin_amdgcn_fdot2(m, atth[q], p, false);
    }
    return p;
}

template <int LAST>
__global__ __launch_bounds__(256) void gat_agg8(
        const __half* __restrict__ xlh, const __half* __restrict__ xr,
        const float* __restrict__ att, const float* __restrict__ bias,
        const int* __restrict__ offsets, const int* __restrict__ csr_src,
        __half* __restrict__ hhi, __half* __restrict__ hlo,
        const float* __restrict__ Wout, const float* __restrict__ bout,
        float* __restrict__ out, int nNodes) {
    int wid  = threadIdx.x >> 6;
    int lane = threadIdx.x & 63;
    int el = lane >> 5;
    int l  = lane & 31;
    int c0 = l * 8;

    half2_t atth[4];
    {
        float a8[8];
        *(float4*)&a8[0] = *(const float4*)&att[c0];
        *(float4*)&a8[4] = *(const float4*)&att[c0 + 4];
        #pragma unroll
        for (int q = 0; q < 4; ++q)
            atth[q] = (half2_t){(_Float16)a8[2 * q], (_Float16)a8[2 * q + 1]};
    }

    int stride = gridDim.x << 2;
    for (int node0 = (blockIdx.x << 2) + wid; node0 < nNodes; node0 += stride) {
        int node = __builtin_amdgcn_readfirstlane(node0);
        half2_t xrh[4];
        {
            uint4 xv = *(const uint4*)&xr[(size_t)node * NCH + c0];  // 8 fp16
            #pragma unroll
            for (int q = 0; q < 4; ++q) xrh[q] = u2h2((&xv.x)[q]);
        }

        int begin = offsets[node], end = offsets[node + 1];
        float denom = 0.f;
        float acc8[8];
        #pragma unroll
        for (int c = 0; c < 8; ++c) acc8[c] = 0.f;

        for (int j = begin; j < end; j += 4) {
            int j1 = j + 1 < end ? j + 1 : end - 1;
            int j2 = j + 2 < end ? j + 2 : end - 1;
            int j3 = j + 3 < end ? j + 3 : end - 1;
            int i0 = csr_src[j];
            int i1 = csr_src[j1];
            int i2 = csr_src[j2];
            int i3 = csr_src[j3];
            int sA = el ? i1 : i0;
            int sB = el ? i3 : i2;
            uint4 rA = *(const uint4*)&xlh[(size_t)sA * NCH + c0];
            uint4 rB = *(const uint4*)&xlh[(size_t)sB * NCH + c0];

            float pA = edge_dot(rA, xrh, atth);
            float pB = edge_dot(rB, xrh, atth);
            #pragma unroll
            for (int off = 1; off < 16; off <<= 1) {
                pA += __shfl_xor(pA, off);
                pB += __shfl_xor(pB, off);
            }
            float exA = (j + el < end)     ? __expf(pA) : 0.f;
            float exB = (j + 2 + el < end) ? __expf(pB) : 0.f;
            denom += exA + exB;
            #pragma unroll
            for (int q = 0; q < 4; ++q) {
                float2 fa = __half22float2(*(const __half2*)&(&rA.x)[q]);
                float2 fb = __half22float2(*(const __half2*)&(&rB.x)[q]);
                acc8[2 * q]     = fmaf(exA, fa.x, acc8[2 * q]);
                acc8[2 * q + 1] = fmaf(exA, fa.y, acc8[2 * q + 1]);
                acc8[2 * q]     = fmaf(exB, fb.x, acc8[2 * q]);
                acc8[2 * q + 1] = fmaf(exB, fb.y, acc8[2 * q + 1]);
            }
        }

        // combine edge-halves
        #pragma unroll
        for (int c = 0; c < 8; ++c) acc8[c] += __shfl_xor(acc8[c], 32);
        denom += __shfl_xor(denom, 32);
        float rd = 1.0f / denom;

        float o8[8], bi8[8];
        *(float4*)&bi8[0] = *(const float4*)&bias[c0];
        *(float4*)&bi8[4] = *(const float4*)&bias[c0 + 4];
        #pragma unroll
        for (int c = 0; c < 8; ++c)
            o8[c] = fmaxf(fmaf(acc8[c], rd, bi8[c]), 0.f);

        if (!LAST) {
            if (el == 0) {
                ushort h8[8], lo8[8];
                #pragma unroll
                for (int c = 0; c < 8; ++c) {
                    __half h = __float2half_rn(o8[c]);
                    h8[c]  = __half_as_ushort(h);
                    lo8[c] = __half_as_ushort(__float2half_rn(o8[c] - __half2float(h)));
                }
                *(uint4*)&hhi[(size_t)node * NCH + c0] = *(uint4*)&h8[0];
                *(uint4*)&hlo[(size_t)node * NCH + c0] = *(uint4*)&lo8[0];
            }
        } else {
            float p0 = 0.f, p1 = 0.f, p2 = 0.f, p3 = 0.f;
            #pragma unroll
            for (int c = 0; c < 8; ++c) {
                float4 w4 = *(const float4*)&Wout[(size_t)(c0 + c) * 4];
                p0 = fmaf(o8[c], w4.x, p0);
                p1 = fmaf(o8[c], w4.y, p1);
                p2 = fmaf(o8[c], w4.z, p2);
                p3 = fmaf(o8[c], w4.w, p3);
            }
            #pragma unroll
            for (int off = 1; off < 32; off <<= 1) {
                p0 += __shfl_xor(p0, off);
                p1 += __shfl_xor(p1, off);
                p2 += __shfl_xor(p2, off);
                p3 += __shfl_xor(p3, off);
            }
            if (lane == 0) {
                float4 r;
                r.x = p0 + bout[0]; r.y = p1 + bout[1];
                r.z = p2 + bout[2]; r.w = p3 + bout[3];
                *(float4*)&out[(size_t)node * 4] = r;
            }
        }
    }
}

// ---------------------------------------------------------------------------
extern "C" void kernel_launch(void* const* d_in, const int* in_sizes, int n_in,
                              void* d_out, int out_size, void* d_ws, size_t ws_size,
                              hipStream_t stream) {
    const float* x  = (const float*)d_in[0];
    const int*   ei = (const int*)d_in[1];
    const float* Wl[3]  = {(const float*)d_in[2], (const float*)d_in[6],  (const float*)d_in[10]};
    const float* Wr[3]  = {(const float*)d_in[3], (const float*)d_in[7],  (const float*)d_in[11]};
    const float* att[3] = {(const float*)d_in[4], (const float*)d_in[8],  (const float*)d_in[12]};
    const float* bb[3]  = {(const float*)d_in[5], (const float*)d_in[9],  (const float*)d_in[13]};
    const float* Wout = (const float*)d_in[14];
    const float* bout = (const float*)d_in[15];

    int Nn   = in_sizes[0] / NCH;       // 20000
    int E    = in_sizes[1] / 2;         // 320000

    size_t NEf = (size_t)Nn * NCH;
    __half* xlh  = (__half*)d_ws;                  // NEf halves
    __half* xrh  = xlh + NEf;                      // NEf halves (now fp16)
    __half* bAhi = xrh + NEf;                      // NEf
    __half* bAlo = bAhi + NEf;
    __half* bBhi = bAlo + NEf;
    __half* bBlo = bBhi + NEf;
    __half* wt   = bBlo + NEf;                     // 6 * 65536
    int*   counts  = (int*)(wt + 6 * 65536);
    int*   offsets = counts + Nn;
    int*   cursor  = offsets + (Nn + 1);
    int*   csr_src = cursor + Nn;

    // wsplit first: transposes weights AND zeroes counts (saves a dispatch)
    WPtrs wp = {{Wl[0], Wr[0], Wl[1], Wr[1], Wl[2], Wr[2]}};
    wsplit_kernel<<<dim3(8, 8, 6), dim3(32, 32), 0, stream>>>(wp, wt, counts, Nn);

    int vthreads = (E >> 2) + Nn;                  // vectorized edges + self loops
    int vblocks  = (vthreads + 255) / 256;
    count_kernel<<<vblocks, 256, 0, stream>>>(ei, E, Nn, counts);
    scan_kernel<<<1, 1024, 0, stream>>>(counts, offsets, cursor, Nn);
    scatter_kernel<<<vblocks, 256, 0, stream>>>(ei, E, Nn, cursor, csr_src);

    int nrt = (Nn + 127) / 128;                    // 157 row tiles
    int prt = ((nrt + 7) / 8) * 8;                 // padded to 8
    int gblocks = prt * 4;                         // 640
    int nblocks = 2048;                            // proven gat grid
    if (nblocks > (Nn + 3) / 4) nblocks = (Nn + 3) / 4;

    // layer 1: A = x (fp32, split in-register)
    dual_gemm_mfma<1><<<gblocks, 256, 0, stream>>>(x, nullptr, nullptr,
                                                   wt, xlh, xrh, Nn);
    gat_agg8<0><<<nblocks, 256, 0, stream>>>(xlh, xrh, att[0], bb[0],
        offsets, csr_src, bAhi, bAlo, nullptr, nullptr, nullptr, Nn);
    // layer 2: A = bufA (fp16 hi/lo)
    dual_gemm_mfma<0><<<gblocks, 256, 0, stream>>>(nullptr, bAhi, bAlo,
                                                   wt + 2 * 65536, xlh, xrh, Nn);
    gat_agg8<0><<<nblocks, 256, 0, stream>>>(xlh, xrh, att[1], bb[1],
        offsets, csr_src, bBhi, bBlo, nullptr, nullptr, nullptr, Nn);
    // layer 3: A = bufB, fused output projection
    dual_gemm_mfma<0><<<gblocks, 256, 0, stream>>>(nullptr, bBhi, bBlo,
                                                   wt + 4 * 65536, xlh, xrh, Nn);
    gat_agg8<1><<<nblocks, 256, 0, stream>>>(xlh, xrh, att[2], bb[2],
        offsets, csr_src, nullptr, nullptr, Wout, bout, (float*)d_out, Nn);
}